// Round 5
// baseline (135.326 us; speedup 1.0000x reference)
//
#include <hip/hip_runtime.h>

// SAHead: B=2, Cenc=326, C=320, dk=dv=64, L=64*64=4096.
// Cosine attention => scores in [-1,1] => exp() stable without max-subtraction
// => split-j partial softmax combines by plain addition.
//
// Pipeline (4 launches):
//   prep    : xpose x/xe -> Xt[b][l][384] bf16 (zero-pad) ; wconv W -> bf16[384]
//   proj    : MFMA GEMM; Q+K fused per block (shared Xt B-frags); V separate.
//             L2-normalize fused in epilogue -> qn/kn [l][64] bf16, V [v][L] bf16
//   attn    : flash-style, split-j partial softmax, LDS-staged K/V
//   combine : sum split partials, divide by rowsum, transpose to [b][v][l]

#define L_DIM 4096
#define KPAD 384
#define NSPLIT 8

typedef __attribute__((ext_vector_type(8))) short bf16x8;  // 8 bf16 (4 VGPRs)
typedef __attribute__((ext_vector_type(4))) float f32x4;   // 4 fp32 acc

__device__ __forceinline__ unsigned short f2bf(float f) {
    // round-to-nearest-even fp32 -> bf16
    unsigned u = __float_as_uint(f);
    u += 0x7fffu + ((u >> 16) & 1u);
    return (unsigned short)(u >> 16);
}

// ---------------------------------------------------------------------------
// Kernel 1: prep = xpose (z in [0,4)) + wconv (z == 4).
// xpose: grid (64 l-tiles, 6 c-tiles): x/xe [c][l] fp32 -> Xt [l][KPAD] bf16.
// wconv: 288 of the 384 (x,y) blocks convert W fp32->bf16 rows padded to KPAD.
// ---------------------------------------------------------------------------
__global__ __launch_bounds__(256) void prep_kernel(
    const float* __restrict__ x, const float* __restrict__ xe,
    const float* __restrict__ Wq, const float* __restrict__ Wk,
    const float* __restrict__ Wv,
    unsigned short* __restrict__ xt_x, unsigned short* __restrict__ xt_xe,
    unsigned short* __restrict__ wbf)
{
    const int z = blockIdx.z;
    if (z == 4) {
        const int bid = blockIdx.y * 64 + blockIdx.x;
        const int idx = bid * 256 + threadIdx.x;
        if (idx >= 3 * 64 * KPAD) return;
        const int t = idx / (64 * KPAD);
        const int rem = idx - t * 64 * KPAD;
        const int d = rem / KPAD, c = rem - d * KPAD;
        const int Cin = (t == 2) ? 320 : 326;
        const float* W = (t == 0) ? Wq : (t == 1 ? Wk : Wv);
        wbf[idx] = (c < Cin) ? f2bf(W[(size_t)d * Cin + c]) : (unsigned short)0;
        return;
    }

    const int src_is_x = z >> 1, b = z & 1;
    const int c0 = blockIdx.y * 64;
    const int l0 = blockIdx.x * 64;
    const int Cin = src_is_x ? 320 : 326;
    const float* src = (src_is_x ? x : xe) + (size_t)b * Cin * L_DIM;
    unsigned short* dst = (src_is_x ? xt_x : xt_xe) + (size_t)b * L_DIM * KPAD;

    __shared__ float tile[64][65];
    const int tid = threadIdx.x;

    for (int it = 0; it < 16; ++it) {
        const int idx = tid + it * 256;
        const int cc = idx >> 6, ll = idx & 63;
        const int c = c0 + cc;
        tile[cc][ll] = (c < Cin) ? src[(size_t)c * L_DIM + l0 + ll] : 0.f;
    }
    __syncthreads();
    for (int it = 0; it < 4; ++it) {
        const int idx = tid + it * 256;
        const int ll = idx >> 4, cq = idx & 15;
        ushort4 o;
        o.x = f2bf(tile[cq * 4 + 0][ll]);
        o.y = f2bf(tile[cq * 4 + 1][ll]);
        o.z = f2bf(tile[cq * 4 + 2][ll]);
        o.w = f2bf(tile[cq * 4 + 3][ll]);
        *(ushort4*)(dst + (size_t)(l0 + ll) * KPAD + c0 + cq * 4) = o;
    }
}

// ---------------------------------------------------------------------------
// Kernel 2: MFMA projection. grid (64 l-tiles, 4): y<2 -> fused Q+K (b=y),
// y>=2 -> V (b=y-2). One wave per block, 64d x 64l tile per tensor; Q+K share
// the Xt B-fragments (12 loads -> 32 MFMA per kstep). ~1 wave/CU, so heavy
// VGPR use (acc 128 + frags ~96) costs nothing in occupancy.
// MFMA 16x16x32 bf16 layouts:
//   A: lane holds A[m=lane&15][k=(lane>>4)*8+j]  (8 contiguous k)
//   B: lane holds B[k=(lane>>4)*8+j][n=lane&15]
//   D: lane holds D[row=(lane>>4)*4+r][col=lane&15]
// ---------------------------------------------------------------------------
__global__ __launch_bounds__(64) void proj_kernel(
    const unsigned short* __restrict__ xt_xe, const unsigned short* __restrict__ xt_x,
    const unsigned short* __restrict__ wbf,
    const float* __restrict__ bq, const float* __restrict__ bk,
    const float* __restrict__ bv,
    unsigned short* __restrict__ qn, unsigned short* __restrict__ kn,
    unsigned short* __restrict__ vbf)
{
    const int zz = blockIdx.y;
    const bool isQK = (zz < 2);
    const int b = zz & 1;
    const int l0 = blockIdx.x * 64;
    const int lane = threadIdx.x;
    const int q = lane >> 4, ln = lane & 15;
    const f32x4 zero4 = (f32x4){0.f, 0.f, 0.f, 0.f};

    if (isQK) {
        const unsigned short* Xt = xt_xe + (size_t)b * L_DIM * KPAD;
        const unsigned short* W0 = wbf;              // Wq
        const unsigned short* W1 = wbf + 64 * KPAD;  // Wk
        const int ksteps = 11;                       // 326 -> 352 cols (padded)

        f32x4 acc[2][4][4];
        #pragma unroll
        for (int t = 0; t < 2; ++t)
            #pragma unroll
            for (int mf = 0; mf < 4; ++mf)
                #pragma unroll
                for (int nf = 0; nf < 4; ++nf) acc[t][mf][nf] = zero4;

        bf16x8 af[2][4], afn[2][4], bfr[4], bfn[4];
        #pragma unroll
        for (int mf = 0; mf < 4; ++mf) {
            af[0][mf] = *(const bf16x8*)(W0 + (size_t)(mf * 16 + ln) * KPAD + q * 8);
            af[1][mf] = *(const bf16x8*)(W1 + (size_t)(mf * 16 + ln) * KPAD + q * 8);
        }
        #pragma unroll
        for (int nf = 0; nf < 4; ++nf)
            bfr[nf] = *(const bf16x8*)(Xt + (size_t)(l0 + nf * 16 + ln) * KPAD + q * 8);

        for (int ks = 0; ks < ksteps; ++ks) {
            if (ks + 1 < ksteps) {
                const int c = (ks + 1) * 32 + q * 8;
                #pragma unroll
                for (int mf = 0; mf < 4; ++mf) {
                    afn[0][mf] = *(const bf16x8*)(W0 + (size_t)(mf * 16 + ln) * KPAD + c);
                    afn[1][mf] = *(const bf16x8*)(W1 + (size_t)(mf * 16 + ln) * KPAD + c);
                }
                #pragma unroll
                for (int nf = 0; nf < 4; ++nf)
                    bfn[nf] = *(const bf16x8*)(Xt + (size_t)(l0 + nf * 16 + ln) * KPAD + c);
            }
            #pragma unroll
            for (int t = 0; t < 2; ++t)
                #pragma unroll
                for (int mf = 0; mf < 4; ++mf)
                    #pragma unroll
                    for (int nf = 0; nf < 4; ++nf)
                        acc[t][mf][nf] = __builtin_amdgcn_mfma_f32_16x16x32_bf16(
                            af[t][mf], bfr[nf], acc[t][mf][nf], 0, 0, 0);
            #pragma unroll
            for (int t = 0; t < 2; ++t)
                #pragma unroll
                for (int mf = 0; mf < 4; ++mf) af[t][mf] = afn[t][mf];
            #pragma unroll
            for (int nf = 0; nf < 4; ++nf) bfr[nf] = bfn[nf];
        }

        #pragma unroll
        for (int t = 0; t < 2; ++t) {
            const float* bias = t ? bk : bq;
            unsigned short* outp = (t ? kn : qn) + (size_t)b * L_DIM * 64;
            #pragma unroll
            for (int mf = 0; mf < 4; ++mf)
                #pragma unroll
                for (int r = 0; r < 4; ++r) {
                    const float bb = bias[mf * 16 + q * 4 + r];
                    #pragma unroll
                    for (int nf = 0; nf < 4; ++nf) acc[t][mf][nf][r] += bb;
                }
            // L2-normalize over d (rows) at fixed l (col)
            #pragma unroll
            for (int nf = 0; nf < 4; ++nf) {
                float s = 0.f;
                #pragma unroll
                for (int mf = 0; mf < 4; ++mf)
                    #pragma unroll
                    for (int r = 0; r < 4; ++r) s += acc[t][mf][nf][r] * acc[t][mf][nf][r];
                s += __shfl_xor(s, 16);
                s += __shfl_xor(s, 32);
                const float rn = 1.0f / fmaxf(sqrtf(s), 1e-6f);
                const size_t lrow = (size_t)(l0 + nf * 16 + ln) * 64;
                #pragma unroll
                for (int mf = 0; mf < 4; ++mf) {
                    ushort4 o;
                    o.x = f2bf(acc[t][mf][nf][0] * rn);
                    o.y = f2bf(acc[t][mf][nf][1] * rn);
                    o.z = f2bf(acc[t][mf][nf][2] * rn);
                    o.w = f2bf(acc[t][mf][nf][3] * rn);
                    *(ushort4*)(outp + lrow + mf * 16 + q * 4) = o;
                }
            }
        }
    } else {
        const unsigned short* Xt = xt_x + (size_t)b * L_DIM * KPAD;
        const unsigned short* W  = wbf + (size_t)2 * 64 * KPAD;
        const int ksteps = 10;   // 320 cols exactly

        f32x4 acc[4][4];
        #pragma unroll
        for (int mf = 0; mf < 4; ++mf)
            #pragma unroll
            for (int nf = 0; nf < 4; ++nf) acc[mf][nf] = zero4;

        bf16x8 af[4], bfr[4], afn[4], bfn[4];
        #pragma unroll
        for (int mf = 0; mf < 4; ++mf)
            af[mf] = *(const bf16x8*)(W + (size_t)(mf * 16 + ln) * KPAD + q * 8);
        #pragma unroll
        for (int nf = 0; nf < 4; ++nf)
            bfr[nf] = *(const bf16x8*)(Xt + (size_t)(l0 + nf * 16 + ln) * KPAD + q * 8);

        for (int ks = 0; ks < ksteps; ++ks) {
            if (ks + 1 < ksteps) {
                const int c = (ks + 1) * 32 + q * 8;
                #pragma unroll
                for (int mf = 0; mf < 4; ++mf)
                    afn[mf] = *(const bf16x8*)(W + (size_t)(mf * 16 + ln) * KPAD + c);
                #pragma unroll
                for (int nf = 0; nf < 4; ++nf)
                    bfn[nf] = *(const bf16x8*)(Xt + (size_t)(l0 + nf * 16 + ln) * KPAD + c);
            }
            #pragma unroll
            for (int mf = 0; mf < 4; ++mf)
                #pragma unroll
                for (int nf = 0; nf < 4; ++nf)
                    acc[mf][nf] = __builtin_amdgcn_mfma_f32_16x16x32_bf16(
                        af[mf], bfr[nf], acc[mf][nf], 0, 0, 0);
            #pragma unroll
            for (int mf = 0; mf < 4; ++mf) af[mf] = afn[mf];
            #pragma unroll
            for (int nf = 0; nf < 4; ++nf) bfr[nf] = bfn[nf];
        }

        unsigned short* outp = vbf + (size_t)b * 64 * L_DIM;
        #pragma unroll
        for (int mf = 0; mf < 4; ++mf)
            #pragma unroll
            for (int r = 0; r < 4; ++r) {
                const float bb = bv[mf * 16 + q * 4 + r];
                const int v = mf * 16 + q * 4 + r;
                #pragma unroll
                for (int nf = 0; nf < 4; ++nf)
                    outp[(size_t)v * L_DIM + l0 + nf * 16 + ln] = f2bf(acc[mf][nf][r] + bb);
            }
    }
}

// ---------------------------------------------------------------------------
// Kernel 3: attention, LDS-staged K/V shared by 4 waves, software-pipelined.
// grid (32, NSPLIT, 2): x = 128-row i-tile, y = j-split, z = b.
// Wave w owns i-strip [32w, 32w+32) as two 16-row substrips.
// ---------------------------------------------------------------------------
__global__ __launch_bounds__(256) void attn_kernel(
    const unsigned short* __restrict__ qn, const unsigned short* __restrict__ kn,
    const unsigned short* __restrict__ vbf,
    float* __restrict__ opart, float* __restrict__ ssum)
{
    const int b = blockIdx.z, split = blockIdx.y;
    const int i0 = blockIdx.x * 128;
    const int tid = threadIdx.x;
    const int w = tid >> 6, lane = tid & 63, q = lane >> 4, ln = lane & 15;

    const unsigned short* Q = qn + (size_t)b * L_DIM * 64;   // [l][64]
    const unsigned short* K = kn + (size_t)b * L_DIM * 64;   // [l][64]
    const unsigned short* V = vbf + (size_t)b * 64 * L_DIM;  // [v][L]

    __shared__ unsigned short Kb[64][72];     // [j][d], +8 pad
    __shared__ unsigned short Vb[64][72];     // [v][j], +8 pad
    __shared__ unsigned short Pl[4][32][72];  // wave-private P strips

    bf16x8 qa[2][2];
    #pragma unroll
    for (int s = 0; s < 2; ++s) {
        const unsigned short* qp = Q + (size_t)(i0 + w * 32 + s * 16 + ln) * 64 + q * 8;
        qa[s][0] = *(const bf16x8*)(qp);
        qa[s][1] = *(const bf16x8*)(qp + 32);
    }

    f32x4 acc[2][4];
    #pragma unroll
    for (int s = 0; s < 2; ++s)
        #pragma unroll
        for (int vf = 0; vf < 4; ++vf) acc[s][vf] = (f32x4){0.f, 0.f, 0.f, 0.f};
    float rowsum[2][4] = {{0.f,0.f,0.f,0.f},{0.f,0.f,0.f,0.f}};
    const f32x4 zero = (f32x4){0.f, 0.f, 0.f, 0.f};

    const int jbase = split * (L_DIM / NSPLIT);
    const int JT = L_DIM / (NSPLIT * 64);   // 8 j-tiles per split

    bf16x8 kst[2], vst[2];
    #pragma unroll
    for (int p = 0; p < 2; ++p) {
        const int idx = p * 256 + tid;
        kst[p] = *(const bf16x8*)(K + (size_t)jbase * 64 + idx * 8);
        vst[p] = *(const bf16x8*)(V + (size_t)(idx >> 3) * L_DIM + jbase + (idx & 7) * 8);
    }
    #pragma unroll
    for (int p = 0; p < 2; ++p) {
        const int idx = p * 256 + tid;
        *(bf16x8*)&Kb[idx >> 3][(idx & 7) * 8] = kst[p];
        *(bf16x8*)&Vb[idx >> 3][(idx & 7) * 8] = vst[p];
    }
    __syncthreads();

    for (int jt = 0; jt < JT; ++jt) {
        if (jt + 1 < JT) {
            const int j0 = jbase + (jt + 1) * 64;
            #pragma unroll
            for (int p = 0; p < 2; ++p) {
                const int idx = p * 256 + tid;
                kst[p] = *(const bf16x8*)(K + (size_t)j0 * 64 + idx * 8);
                vst[p] = *(const bf16x8*)(V + (size_t)(idx >> 3) * L_DIM + j0 + (idx & 7) * 8);
            }
        }

        bf16x8 kf[4][2];
        #pragma unroll
        for (int jf = 0; jf < 4; ++jf) {
            kf[jf][0] = *(const bf16x8*)&Kb[jf * 16 + ln][q * 8];
            kf[jf][1] = *(const bf16x8*)&Kb[jf * 16 + ln][q * 8 + 32];
        }

        #pragma unroll
        for (int s = 0; s < 2; ++s) {
            f32x4 sv[4];
            #pragma unroll
            for (int jf = 0; jf < 4; ++jf) {
                sv[jf] = __builtin_amdgcn_mfma_f32_16x16x32_bf16(qa[s][0], kf[jf][0], zero, 0, 0, 0);
                sv[jf] = __builtin_amdgcn_mfma_f32_16x16x32_bf16(qa[s][1], kf[jf][1], sv[jf], 0, 0, 0);
            }
            #pragma unroll
            for (int jf = 0; jf < 4; ++jf)
                #pragma unroll
                for (int r = 0; r < 4; ++r) {
                    const float p = __expf(sv[jf][r]);
                    rowsum[s][r] += p;
                    Pl[w][s * 16 + q * 4 + r][jf * 16 + ln] = f2bf(p);
                }
        }

        bf16x8 vfr[4][2];
        #pragma unroll
        for (int vf = 0; vf < 4; ++vf) {
            vfr[vf][0] = *(const bf16x8*)&Vb[vf * 16 + ln][q * 8];
            vfr[vf][1] = *(const bf16x8*)&Vb[vf * 16 + ln][q * 8 + 32];
        }

        #pragma unroll
        for (int s = 0; s < 2; ++s) {
            const bf16x8 pa0 = *(const bf16x8*)&Pl[w][s * 16 + ln][q * 8];
            const bf16x8 pa1 = *(const bf16x8*)&Pl[w][s * 16 + ln][q * 8 + 32];
            #pragma unroll
            for (int vf = 0; vf < 4; ++vf) {
                acc[s][vf] = __builtin_amdgcn_mfma_f32_16x16x32_bf16(pa0, vfr[vf][0], acc[s][vf], 0, 0, 0);
                acc[s][vf] = __builtin_amdgcn_mfma_f32_16x16x32_bf16(pa1, vfr[vf][1], acc[s][vf], 0, 0, 0);
            }
        }

        __syncthreads();
        if (jt + 1 < JT) {
            #pragma unroll
            for (int p = 0; p < 2; ++p) {
                const int idx = p * 256 + tid;
                *(bf16x8*)&Kb[idx >> 3][(idx & 7) * 8] = kst[p];
                *(bf16x8*)&Vb[idx >> 3][(idx & 7) * 8] = vst[p];
            }
            __syncthreads();
        }
    }

    #pragma unroll
    for (int off = 1; off < 16; off <<= 1)
        #pragma unroll
        for (int s = 0; s < 2; ++s)
            #pragma unroll
            for (int r = 0; r < 4; ++r)
                rowsum[s][r] += __shfl_xor(rowsum[s][r], off);

    float* Op = opart + ((size_t)(b * NSPLIT + split) * L_DIM + i0 + w * 32) * 64;
    #pragma unroll
    for (int s = 0; s < 2; ++s)
        #pragma unroll
        for (int vf = 0; vf < 4; ++vf)
            #pragma unroll
            for (int r = 0; r < 4; ++r)
                Op[(s * 16 + q * 4 + r) * 64 + vf * 16 + ln] = acc[s][vf][r];

    if (ln == 0) {
        #pragma unroll
        for (int s = 0; s < 2; ++s)
            #pragma unroll
            for (int r = 0; r < 4; ++r)
                ssum[(size_t)(b * NSPLIT + split) * L_DIM + i0 + w * 32 + s * 16 + q * 4 + r]
                    = rowsum[s][r];
    }
}

// ---------------------------------------------------------------------------
// Kernel 4: sum the NSPLIT partials, divide by rowsum, transpose to [b][v][l].
// ---------------------------------------------------------------------------
__global__ __launch_bounds__(256) void combine_kernel(
    const float* __restrict__ opart, const float* __restrict__ ssum,
    float* __restrict__ out)
{
    const int b = blockIdx.y;
    const int i0 = blockIdx.x * 64;
    const int tid = threadIdx.x;
    __shared__ float t[64][65];
    __shared__ float sinv[64];

    if (tid < 64) {
        float s = 0.f;
        for (int sp = 0; sp < NSPLIT; ++sp)
            s += ssum[(size_t)(b * NSPLIT + sp) * L_DIM + i0 + tid];
        sinv[tid] = 1.0f / s;
    }
    __syncthreads();
    for (int idx = tid; idx < 4096; idx += 256) {
        const int i = idx >> 6, v = idx & 63;
        float a = 0.f;
        for (int sp = 0; sp < NSPLIT; ++sp)
            a += opart[((size_t)(b * NSPLIT + sp) * L_DIM + i0 + i) * 64 + v];
        t[i][v] = a;
    }
    __syncthreads();
    for (int idx = tid; idx < 4096; idx += 256) {
        const int v = idx >> 6, i = idx & 63;
        out[((size_t)(b * 64 + v)) * L_DIM + i0 + i] = t[i][v] * sinv[i];
    }
}

// ---------------------------------------------------------------------------
extern "C" void kernel_launch(void* const* d_in, const int* in_sizes, int n_in,
                              void* d_out, int out_size, void* d_ws, size_t ws_size,
                              hipStream_t stream)
{
    const float* x  = (const float*)d_in[0];
    const float* xe = (const float*)d_in[1];
    const float* Wq = (const float*)d_in[2];
    const float* bq = (const float*)d_in[3];
    const float* Wk = (const float*)d_in[4];
    const float* bk = (const float*)d_in[5];
    const float* Wv = (const float*)d_in[6];
    const float* bv = (const float*)d_in[7];
    float* out = (float*)d_out;

    // ws layout (24 MB): op (16 MB) overlaps xt buffers (dead after proj;
    // attn writes op strictly after proj in stream order).
    char* ws = (char*)d_ws;
    unsigned short* qn   = (unsigned short*)(ws);                    // 0..1 MB
    unsigned short* kn   = (unsigned short*)(ws + (1u << 20));       // 1..2 MB
    unsigned short* vbf  = (unsigned short*)(ws + (2u << 20));       // 2..3 MB
    float*          ss   = (float*)(ws + (3u << 20));                // 3..3.25 MB
    unsigned short* wb   = (unsigned short*)(ws + (3u << 20) + (512u << 10));
    unsigned short* xtxe = (unsigned short*)(ws + (4u << 20));       // 4..10 MB
    unsigned short* xtx  = (unsigned short*)(ws + (10u << 20));      // 10..16 MB
    float*          op   = (float*)(ws + (8u << 20));                // 8..24 MB (overlaps xt)

    prep_kernel<<<dim3(64, 6, 5), 256, 0, stream>>>(x, xe, Wq, Wk, Wv, xtx, xtxe, wb);
    proj_kernel<<<dim3(64, 4), 64, 0, stream>>>(xtxe, xtx, wb, bq, bk, bv, qn, kn, vbf);
    attn_kernel<<<dim3(32, NSPLIT, 2), 256, 0, stream>>>(qn, kn, vbf, op, ss);
    combine_kernel<<<dim3(64, 2), 256, 0, stream>>>(op, ss, out);
}

// Round 6
// 128.380 us; speedup vs baseline: 1.0541x; 1.0541x over previous
//
#include <hip/hip_runtime.h>

// SAHead: B=2, Cenc=326, C=320, dk=dv=64, L=64*64=4096.
// Cosine attention => scores in [-1,1] => exp() stable without max-subtraction
// => split-j partial softmax combines by plain addition.
//
// Pipeline (4 launches):
//   prep    : xpose x/xe -> Xt[b][l][384] bf16 (zero-pad) ; wconv W -> bf16[384]
//   proj    : MFMA GEMM per tensor; L2-normalize fused -> qn/kn [l][64], V [v][L]
//   attn    : flash-style, split-j partial softmax, LDS-staged K/V.
//             Computes S^T = K.Q^T and O^T = V.P^T (A/B frags have identical
//             lane layouts, so operand-swapping is free) => P lands j-contiguous
//             (b64 LDS writes) and O lands v-contiguous (float4 stores).
//   combine : sum split partials, divide by rowsum, transpose to [b][v][l]

#define L_DIM 4096
#define KPAD 384
#define NSPLIT 8

typedef __attribute__((ext_vector_type(8))) short bf16x8;  // 8 bf16 (4 VGPRs)
typedef __attribute__((ext_vector_type(4))) float f32x4;   // 4 fp32 acc

__device__ __forceinline__ unsigned short f2bf(float f) {
    // round-to-nearest-even fp32 -> bf16
    unsigned u = __float_as_uint(f);
    u += 0x7fffu + ((u >> 16) & 1u);
    return (unsigned short)(u >> 16);
}

// ---------------------------------------------------------------------------
// Kernel 1: prep = xpose (z in [0,4)) + wconv (z == 4).
// ---------------------------------------------------------------------------
__global__ __launch_bounds__(256) void prep_kernel(
    const float* __restrict__ x, const float* __restrict__ xe,
    const float* __restrict__ Wq, const float* __restrict__ Wk,
    const float* __restrict__ Wv,
    unsigned short* __restrict__ xt_x, unsigned short* __restrict__ xt_xe,
    unsigned short* __restrict__ wbf)
{
    const int z = blockIdx.z;
    if (z == 4) {
        const int bid = blockIdx.y * 64 + blockIdx.x;
        const int idx = bid * 256 + threadIdx.x;
        if (idx >= 3 * 64 * KPAD) return;
        const int t = idx / (64 * KPAD);
        const int rem = idx - t * 64 * KPAD;
        const int d = rem / KPAD, c = rem - d * KPAD;
        const int Cin = (t == 2) ? 320 : 326;
        const float* W = (t == 0) ? Wq : (t == 1 ? Wk : Wv);
        wbf[idx] = (c < Cin) ? f2bf(W[(size_t)d * Cin + c]) : (unsigned short)0;
        return;
    }

    const int src_is_x = z >> 1, b = z & 1;
    const int c0 = blockIdx.y * 64;
    const int l0 = blockIdx.x * 64;
    const int Cin = src_is_x ? 320 : 326;
    const float* src = (src_is_x ? x : xe) + (size_t)b * Cin * L_DIM;
    unsigned short* dst = (src_is_x ? xt_x : xt_xe) + (size_t)b * L_DIM * KPAD;

    __shared__ float tile[64][65];
    const int tid = threadIdx.x;

    for (int it = 0; it < 16; ++it) {
        const int idx = tid + it * 256;
        const int cc = idx >> 6, ll = idx & 63;
        const int c = c0 + cc;
        tile[cc][ll] = (c < Cin) ? src[(size_t)c * L_DIM + l0 + ll] : 0.f;
    }
    __syncthreads();
    for (int it = 0; it < 4; ++it) {
        const int idx = tid + it * 256;
        const int ll = idx >> 4, cq = idx & 15;
        ushort4 o;
        o.x = f2bf(tile[cq * 4 + 0][ll]);
        o.y = f2bf(tile[cq * 4 + 1][ll]);
        o.z = f2bf(tile[cq * 4 + 2][ll]);
        o.w = f2bf(tile[cq * 4 + 3][ll]);
        *(ushort4*)(dst + (size_t)(l0 + ll) * KPAD + c0 + cq * 4) = o;
    }
}

// ---------------------------------------------------------------------------
// Kernel 2: MFMA projection with fused L2-normalize (Q,K) / bf16 store (V).
// One wave per block computes a 64d x 64l tile. grid (64 l-tiles, 6).
// MFMA 16x16x32 bf16 layouts:
//   A: lane holds A[m=lane&15][k=(lane>>4)*8+j]  (8 contiguous k)
//   B: lane holds B[k=(lane>>4)*8+j][n=lane&15]  (same register pattern as A)
//   D: lane holds D[row=(lane>>4)*4+r][col=lane&15]
// ---------------------------------------------------------------------------
__global__ __launch_bounds__(64) void proj_kernel(
    const unsigned short* __restrict__ xt_xe, const unsigned short* __restrict__ xt_x,
    const unsigned short* __restrict__ wbf,
    const float* __restrict__ bq, const float* __restrict__ bk,
    const float* __restrict__ bv,
    unsigned short* __restrict__ qn, unsigned short* __restrict__ kn,
    unsigned short* __restrict__ vbf)
{
    const int z = blockIdx.y;
    const int tensor = z >> 1, b = z & 1;
    const int l0 = blockIdx.x * 64;
    const int lane = threadIdx.x;
    const int q = lane >> 4, ln = lane & 15;

    const unsigned short* Xt = (tensor == 2 ? xt_x : xt_xe) + (size_t)b * L_DIM * KPAD;
    const unsigned short* W  = wbf + (size_t)tensor * 64 * KPAD;
    const float* bias = (tensor == 0) ? bq : (tensor == 1 ? bk : bv);
    const int ksteps = (tensor == 2) ? 10 : 11;

    f32x4 acc[4][4];
    #pragma unroll
    for (int mf = 0; mf < 4; ++mf)
        #pragma unroll
        for (int nf = 0; nf < 4; ++nf) acc[mf][nf] = (f32x4){0.f, 0.f, 0.f, 0.f};

    bf16x8 af[4], bfr[4], afn[4], bfn[4];
    #pragma unroll
    for (int mf = 0; mf < 4; ++mf)
        af[mf] = *(const bf16x8*)(W + (size_t)(mf * 16 + ln) * KPAD + q * 8);
    #pragma unroll
    for (int nf = 0; nf < 4; ++nf)
        bfr[nf] = *(const bf16x8*)(Xt + (size_t)(l0 + nf * 16 + ln) * KPAD + q * 8);

    for (int ks = 0; ks < ksteps; ++ks) {
        if (ks + 1 < ksteps) {
            const int c = (ks + 1) * 32 + q * 8;
            #pragma unroll
            for (int mf = 0; mf < 4; ++mf)
                afn[mf] = *(const bf16x8*)(W + (size_t)(mf * 16 + ln) * KPAD + c);
            #pragma unroll
            for (int nf = 0; nf < 4; ++nf)
                bfn[nf] = *(const bf16x8*)(Xt + (size_t)(l0 + nf * 16 + ln) * KPAD + c);
        }
        #pragma unroll
        for (int mf = 0; mf < 4; ++mf)
            #pragma unroll
            for (int nf = 0; nf < 4; ++nf)
                acc[mf][nf] = __builtin_amdgcn_mfma_f32_16x16x32_bf16(
                    af[mf], bfr[nf], acc[mf][nf], 0, 0, 0);
        #pragma unroll
        for (int mf = 0; mf < 4; ++mf) af[mf] = afn[mf];
        #pragma unroll
        for (int nf = 0; nf < 4; ++nf) bfr[nf] = bfn[nf];
    }

    #pragma unroll
    for (int mf = 0; mf < 4; ++mf)
        #pragma unroll
        for (int r = 0; r < 4; ++r) {
            const float bb = bias[mf * 16 + q * 4 + r];
            #pragma unroll
            for (int nf = 0; nf < 4; ++nf) acc[mf][nf][r] += bb;
        }

    if (tensor < 2) {
        unsigned short* outp = (tensor ? kn : qn) + (size_t)b * L_DIM * 64;
        #pragma unroll
        for (int nf = 0; nf < 4; ++nf) {
            float s = 0.f;
            #pragma unroll
            for (int mf = 0; mf < 4; ++mf)
                #pragma unroll
                for (int r = 0; r < 4; ++r) s += acc[mf][nf][r] * acc[mf][nf][r];
            s += __shfl_xor(s, 16);
            s += __shfl_xor(s, 32);
            const float rn = 1.0f / fmaxf(sqrtf(s), 1e-6f);
            const size_t lrow = (size_t)(l0 + nf * 16 + ln) * 64;
            #pragma unroll
            for (int mf = 0; mf < 4; ++mf) {
                ushort4 o;
                o.x = f2bf(acc[mf][nf][0] * rn);
                o.y = f2bf(acc[mf][nf][1] * rn);
                o.z = f2bf(acc[mf][nf][2] * rn);
                o.w = f2bf(acc[mf][nf][3] * rn);
                *(ushort4*)(outp + lrow + mf * 16 + q * 4) = o;
            }
        }
    } else {
        unsigned short* outp = vbf + (size_t)b * 64 * L_DIM;
        #pragma unroll
        for (int mf = 0; mf < 4; ++mf)
            #pragma unroll
            for (int r = 0; r < 4; ++r) {
                const int v = mf * 16 + q * 4 + r;
                #pragma unroll
                for (int nf = 0; nf < 4; ++nf)
                    outp[(size_t)v * L_DIM + l0 + nf * 16 + ln] = f2bf(acc[mf][nf][r]);
            }
    }
}

// ---------------------------------------------------------------------------
// Kernel 3: attention, LDS-staged K/V, S^T/O^T formulation.
// grid (32, NSPLIT, 2): x = 128-row i-tile, y = j-split, z = b. 4 waves;
// wave w owns i-strip [32w,32w+32) as two 16-row substrips (i = strip + ln).
//  S^T = mfma(A=K-frag, B=Q-frag): lane gets S[i=ln][j=jf*16+q*4+r]
//    -> P = exp(S) packed as ONE ds_write_b64 per (s,jf); rowsum per-lane.
//  O^T = mfma(A=V-frag, B=P-frag): lane gets O[i=ln][v=vf*16+q*4+r]
//    -> float4 epilogue stores.
// ---------------------------------------------------------------------------
__global__ __launch_bounds__(256) void attn_kernel(
    const unsigned short* __restrict__ qn, const unsigned short* __restrict__ kn,
    const unsigned short* __restrict__ vbf,
    float* __restrict__ opart, float* __restrict__ ssum)
{
    const int b = blockIdx.z, split = blockIdx.y;
    const int i0 = blockIdx.x * 128;
    const int tid = threadIdx.x;
    const int w = tid >> 6, lane = tid & 63, q = lane >> 4, ln = lane & 15;

    const unsigned short* Q = qn + (size_t)b * L_DIM * 64;   // [l][64]
    const unsigned short* K = kn + (size_t)b * L_DIM * 64;   // [l][64]
    const unsigned short* V = vbf + (size_t)b * 64 * L_DIM;  // [v][L]

    __shared__ unsigned short Kb[64][72];     // [j][d], +8 pad
    __shared__ unsigned short Vb[64][72];     // [v][j], +8 pad
    __shared__ unsigned short Pl[4][32][72];  // wave-private P strips [i][j]

    // Q frags (serve as MFMA B-operand): lane holds Q[i=strip+ln][d=q*8..+7]
    bf16x8 qa[2][2];
    #pragma unroll
    for (int s = 0; s < 2; ++s) {
        const unsigned short* qp = Q + (size_t)(i0 + w * 32 + s * 16 + ln) * 64 + q * 8;
        qa[s][0] = *(const bf16x8*)(qp);
        qa[s][1] = *(const bf16x8*)(qp + 32);
    }

    f32x4 acc[2][4];   // [s][vf]: O[i=ln][v=vf*16+q*4+r]
    #pragma unroll
    for (int s = 0; s < 2; ++s)
        #pragma unroll
        for (int vf = 0; vf < 4; ++vf) acc[s][vf] = (f32x4){0.f, 0.f, 0.f, 0.f};
    float rowsum[2] = {0.f, 0.f};
    const f32x4 zero = (f32x4){0.f, 0.f, 0.f, 0.f};

    const int jbase = split * (L_DIM / NSPLIT);
    const int JT = L_DIM / (NSPLIT * 64);   // 8 j-tiles per split

    bf16x8 kst[2], vst[2];
    #pragma unroll
    for (int p = 0; p < 2; ++p) {
        const int idx = p * 256 + tid;
        kst[p] = *(const bf16x8*)(K + (size_t)jbase * 64 + idx * 8);
        vst[p] = *(const bf16x8*)(V + (size_t)(idx >> 3) * L_DIM + jbase + (idx & 7) * 8);
    }
    #pragma unroll
    for (int p = 0; p < 2; ++p) {
        const int idx = p * 256 + tid;
        *(bf16x8*)&Kb[idx >> 3][(idx & 7) * 8] = kst[p];
        *(bf16x8*)&Vb[idx >> 3][(idx & 7) * 8] = vst[p];
    }
    __syncthreads();

    for (int jt = 0; jt < JT; ++jt) {
        if (jt + 1 < JT) {
            const int j0 = jbase + (jt + 1) * 64;
            #pragma unroll
            for (int p = 0; p < 2; ++p) {
                const int idx = p * 256 + tid;
                kst[p] = *(const bf16x8*)(K + (size_t)j0 * 64 + idx * 8);
                vst[p] = *(const bf16x8*)(V + (size_t)(idx >> 3) * L_DIM + j0 + (idx & 7) * 8);
            }
        }

        // K frags (A-operand): lane holds K[j=jf*16+ln][d=q*8..+7]
        bf16x8 kf[4][2];
        #pragma unroll
        for (int jf = 0; jf < 4; ++jf) {
            kf[jf][0] = *(const bf16x8*)&Kb[jf * 16 + ln][q * 8];
            kf[jf][1] = *(const bf16x8*)&Kb[jf * 16 + ln][q * 8 + 32];
        }

        // S^T = K.Q^T ; P = exp(S); b64 write j-contiguous into strip [i][j]
        #pragma unroll
        for (int s = 0; s < 2; ++s) {
            #pragma unroll
            for (int jf = 0; jf < 4; ++jf) {
                f32x4 st;
                st = __builtin_amdgcn_mfma_f32_16x16x32_bf16(kf[jf][0], qa[s][0], zero, 0, 0, 0);
                st = __builtin_amdgcn_mfma_f32_16x16x32_bf16(kf[jf][1], qa[s][1], st, 0, 0, 0);
                const float p0 = __expf(st[0]);
                const float p1 = __expf(st[1]);
                const float p2 = __expf(st[2]);
                const float p3 = __expf(st[3]);
                rowsum[s] += (p0 + p1) + (p2 + p3);
                ushort4 pk;
                pk.x = f2bf(p0); pk.y = f2bf(p1); pk.z = f2bf(p2); pk.w = f2bf(p3);
                *(ushort4*)&Pl[w][s * 16 + ln][jf * 16 + q * 4] = pk;
            }
        }

        // V frags (A-operand): lane holds V[v=vf*16+ln][j=q*8..+7]
        bf16x8 vfr[4][2];
        #pragma unroll
        for (int vf = 0; vf < 4; ++vf) {
            vfr[vf][0] = *(const bf16x8*)&Vb[vf * 16 + ln][q * 8];
            vfr[vf][1] = *(const bf16x8*)&Vb[vf * 16 + ln][q * 8 + 32];
        }

        // O^T += V.P^T  (P frag as B-operand: lane holds P[i=ln][j=q*8..+7])
        #pragma unroll
        for (int s = 0; s < 2; ++s) {
            const bf16x8 pb0 = *(const bf16x8*)&Pl[w][s * 16 + ln][q * 8];
            const bf16x8 pb1 = *(const bf16x8*)&Pl[w][s * 16 + ln][q * 8 + 32];
            #pragma unroll
            for (int vf = 0; vf < 4; ++vf) {
                acc[s][vf] = __builtin_amdgcn_mfma_f32_16x16x32_bf16(vfr[vf][0], pb0, acc[s][vf], 0, 0, 0);
                acc[s][vf] = __builtin_amdgcn_mfma_f32_16x16x32_bf16(vfr[vf][1], pb1, acc[s][vf], 0, 0, 0);
            }
        }

        __syncthreads();
        if (jt + 1 < JT) {
            #pragma unroll
            for (int p = 0; p < 2; ++p) {
                const int idx = p * 256 + tid;
                *(bf16x8*)&Kb[idx >> 3][(idx & 7) * 8] = kst[p];
                *(bf16x8*)&Vb[idx >> 3][(idx & 7) * 8] = vst[p];
            }
            __syncthreads();
        }
    }

    // rowsum: lane holds partial over its j-quads at i=ln; sum across quads
    #pragma unroll
    for (int s = 0; s < 2; ++s) {
        rowsum[s] += __shfl_xor(rowsum[s], 16);
        rowsum[s] += __shfl_xor(rowsum[s], 32);
    }

    // O epilogue: float4 stores, i = strip + ln, v = vf*16+q*4..+3
    float* Op = opart + ((size_t)(b * NSPLIT + split) * L_DIM + i0 + w * 32) * 64;
    #pragma unroll
    for (int s = 0; s < 2; ++s)
        #pragma unroll
        for (int vf = 0; vf < 4; ++vf) {
            float4 o;
            o.x = acc[s][vf][0]; o.y = acc[s][vf][1];
            o.z = acc[s][vf][2]; o.w = acc[s][vf][3];
            *(float4*)&Op[(s * 16 + ln) * 64 + vf * 16 + q * 4] = o;
        }

    if (q == 0) {
        #pragma unroll
        for (int s = 0; s < 2; ++s)
            ssum[(size_t)(b * NSPLIT + split) * L_DIM + i0 + w * 32 + s * 16 + ln]
                = rowsum[s];
    }
}

// ---------------------------------------------------------------------------
// Kernel 4: sum the NSPLIT partials, divide by rowsum, transpose to [b][v][l].
// ---------------------------------------------------------------------------
__global__ __launch_bounds__(256) void combine_kernel(
    const float* __restrict__ opart, const float* __restrict__ ssum,
    float* __restrict__ out)
{
    const int b = blockIdx.y;
    const int i0 = blockIdx.x * 64;
    const int tid = threadIdx.x;
    __shared__ float t[64][65];
    __shared__ float sinv[64];

    if (tid < 64) {
        float s = 0.f;
        for (int sp = 0; sp < NSPLIT; ++sp)
            s += ssum[(size_t)(b * NSPLIT + sp) * L_DIM + i0 + tid];
        sinv[tid] = 1.0f / s;
    }
    __syncthreads();
    for (int idx = tid; idx < 4096; idx += 256) {
        const int i = idx >> 6, v = idx & 63;
        float a = 0.f;
        for (int sp = 0; sp < NSPLIT; ++sp)
            a += opart[((size_t)(b * NSPLIT + sp) * L_DIM + i0 + i) * 64 + v];
        t[i][v] = a;
    }
    __syncthreads();
    for (int idx = tid; idx < 4096; idx += 256) {
        const int v = idx >> 6, i = idx & 63;
        out[((size_t)(b * 64 + v)) * L_DIM + i0 + i] = t[i][v] * sinv[i];
    }
}

// ---------------------------------------------------------------------------
extern "C" void kernel_launch(void* const* d_in, const int* in_sizes, int n_in,
                              void* d_out, int out_size, void* d_ws, size_t ws_size,
                              hipStream_t stream)
{
    const float* x  = (const float*)d_in[0];
    const float* xe = (const float*)d_in[1];
    const float* Wq = (const float*)d_in[2];
    const float* bq = (const float*)d_in[3];
    const float* Wk = (const float*)d_in[4];
    const float* bk = (const float*)d_in[5];
    const float* Wv = (const float*)d_in[6];
    const float* bv = (const float*)d_in[7];
    float* out = (float*)d_out;

    // ws layout (24 MB): op (16 MB) overlaps xt buffers (dead after proj;
    // attn writes op strictly after proj in stream order).
    char* ws = (char*)d_ws;
    unsigned short* qn   = (unsigned short*)(ws);                    // 0..1 MB
    unsigned short* kn   = (unsigned short*)(ws + (1u << 20));       // 1..2 MB
    unsigned short* vbf  = (unsigned short*)(ws + (2u << 20));       // 2..3 MB
    float*          ss   = (float*)(ws + (3u << 20));                // 3..3.25 MB
    unsigned short* wb   = (unsigned short*)(ws + (3u << 20) + (512u << 10));
    unsigned short* xtxe = (unsigned short*)(ws + (4u << 20));       // 4..10 MB
    unsigned short* xtx  = (unsigned short*)(ws + (10u << 20));      // 10..16 MB
    float*          op   = (float*)(ws + (8u << 20));                // 8..24 MB (overlaps xt)

    prep_kernel<<<dim3(64, 6, 5), 256, 0, stream>>>(x, xe, Wq, Wk, Wv, xtx, xtxe, wb);
    proj_kernel<<<dim3(64, 6), 64, 0, stream>>>(xtxe, xtx, wb, bq, bk, bv, qn, kn, vbf);
    attn_kernel<<<dim3(32, NSPLIT, 2), 256, 0, stream>>>(qn, kn, vbf, op, ss);
    combine_kernel<<<dim3(64, 2), 256, 0, stream>>>(op, ss, out);
}

// Round 7
// 112.054 us; speedup vs baseline: 1.2077x; 1.1457x over previous
//
#include <hip/hip_runtime.h>

// SAHead: B=2, Cenc=326, C=320, dk=dv=64, L=64*64=4096.
// Cosine attention => scores in [-1,1] => exp() stable without max-subtraction
// => split-j partial softmax combines by plain addition.
//
// Pipeline (4 launches):
//   prep    : xpose x/xe -> Xt[b][l][384] bf16 (zero-pad) ; wconv W -> bf16[384]
//   proj    : MFMA GEMM, 2 waves K-split + LDS reduce; L2-normalize fused.
//   attn    : flash-style, split-j partial softmax, LDS-staged K/V, S^T/O^T
//             formulation; partials stored bf16.
//   combine : sum bf16 split partials, divide by rowsum, transpose to [b][v][l]

#define L_DIM 4096
#define KPAD 384
#define NSPLIT 8

typedef __attribute__((ext_vector_type(8))) short bf16x8;  // 8 bf16 (4 VGPRs)
typedef __attribute__((ext_vector_type(4))) float f32x4;   // 4 fp32 acc

__device__ __forceinline__ unsigned short f2bf(float f) {
    // round-to-nearest-even fp32 -> bf16
    unsigned u = __float_as_uint(f);
    u += 0x7fffu + ((u >> 16) & 1u);
    return (unsigned short)(u >> 16);
}

__device__ __forceinline__ float bf2f(unsigned short h) {
    return __uint_as_float((unsigned)h << 16);
}

// ---------------------------------------------------------------------------
// Kernel 1: prep = xpose (z in [0,4)) + wconv (z == 4).
// xpose: float4 global loads -> LDS [c][l] fp32 tile -> ushort4 transposed out.
// ---------------------------------------------------------------------------
__global__ __launch_bounds__(256) void prep_kernel(
    const float* __restrict__ x, const float* __restrict__ xe,
    const float* __restrict__ Wq, const float* __restrict__ Wk,
    const float* __restrict__ Wv,
    unsigned short* __restrict__ xt_x, unsigned short* __restrict__ xt_xe,
    unsigned short* __restrict__ wbf)
{
    const int z = blockIdx.z;
    if (z == 4) {
        const int bid = blockIdx.y * 64 + blockIdx.x;
        const int idx = bid * 256 + threadIdx.x;
        if (idx >= 3 * 64 * KPAD) return;
        const int t = idx / (64 * KPAD);
        const int rem = idx - t * 64 * KPAD;
        const int d = rem / KPAD, c = rem - d * KPAD;
        const int Cin = (t == 2) ? 320 : 326;
        const float* W = (t == 0) ? Wq : (t == 1 ? Wk : Wv);
        wbf[idx] = (c < Cin) ? f2bf(W[(size_t)d * Cin + c]) : (unsigned short)0;
        return;
    }

    const int src_is_x = z >> 1, b = z & 1;
    const int c0 = blockIdx.y * 64;
    const int l0 = blockIdx.x * 64;
    const int Cin = src_is_x ? 320 : 326;
    const float* src = (src_is_x ? x : xe) + (size_t)b * Cin * L_DIM;
    unsigned short* dst = (src_is_x ? xt_x : xt_xe) + (size_t)b * L_DIM * KPAD;

    __shared__ float tile[64][65];
    const int tid = threadIdx.x;

    #pragma unroll
    for (int it = 0; it < 4; ++it) {
        const int idx = tid + it * 256;          // 1024 float4 loads
        const int cc = idx >> 4, lq = idx & 15;  // l = lq*4
        const int c = c0 + cc;
        float4 v = make_float4(0.f, 0.f, 0.f, 0.f);
        if (c < Cin) v = *(const float4*)(src + (size_t)c * L_DIM + l0 + lq * 4);
        tile[cc][lq * 4 + 0] = v.x;
        tile[cc][lq * 4 + 1] = v.y;
        tile[cc][lq * 4 + 2] = v.z;
        tile[cc][lq * 4 + 3] = v.w;
    }
    __syncthreads();
    #pragma unroll
    for (int it = 0; it < 4; ++it) {
        const int idx = tid + it * 256;
        const int ll = idx >> 4, cq = idx & 15;
        ushort4 o;
        o.x = f2bf(tile[cq * 4 + 0][ll]);
        o.y = f2bf(tile[cq * 4 + 1][ll]);
        o.z = f2bf(tile[cq * 4 + 2][ll]);
        o.w = f2bf(tile[cq * 4 + 3][ll]);
        *(ushort4*)(dst + (size_t)(l0 + ll) * KPAD + c0 + cq * 4) = o;
    }
}

// ---------------------------------------------------------------------------
// Kernel 2: MFMA projection, 2-wave K-split. grid (64 l-tiles, 6), 128 thr.
// Wave w handles ksteps [6w, 6w+6) of 12 (K=384, zero-padded so split exact).
// Wave 1 writes partial acc to LDS; wave 0 adds + bias + (Q,K: L2-norm) store.
// MFMA 16x16x32 bf16 layouts:
//   A: lane holds A[m=lane&15][k=(lane>>4)*8+j]  (8 contiguous k)
//   B: lane holds B[k=(lane>>4)*8+j][n=lane&15]  (same register pattern as A)
//   D: lane holds D[row=(lane>>4)*4+r][col=lane&15]
// ---------------------------------------------------------------------------
__global__ __launch_bounds__(128) void proj_kernel(
    const unsigned short* __restrict__ xt_xe, const unsigned short* __restrict__ xt_x,
    const unsigned short* __restrict__ wbf,
    const float* __restrict__ bq, const float* __restrict__ bk,
    const float* __restrict__ bv,
    unsigned short* __restrict__ qn, unsigned short* __restrict__ kn,
    unsigned short* __restrict__ vbf)
{
    const int z = blockIdx.y;
    const int tensor = z >> 1, b = z & 1;
    const int l0 = blockIdx.x * 64;
    const int tid = threadIdx.x;
    const int w = tid >> 6, lane = tid & 63;
    const int q = lane >> 4, ln = lane & 15;

    const unsigned short* Xt = (tensor == 2 ? xt_x : xt_xe) + (size_t)b * L_DIM * KPAD;
    const unsigned short* W  = wbf + (size_t)tensor * 64 * KPAD;
    const float* bias = (tensor == 0) ? bq : (tensor == 1 ? bk : bv);

    __shared__ float red[64][68];   // wave-1 partial acc: [lane][frag*4..+3]

    f32x4 acc[4][4];
    #pragma unroll
    for (int mf = 0; mf < 4; ++mf)
        #pragma unroll
        for (int nf = 0; nf < 4; ++nf) acc[mf][nf] = (f32x4){0.f, 0.f, 0.f, 0.f};

    const int kbase = w * 6 * 32;   // this wave's K range: 6 steps of 32

    bf16x8 af[4], bfr[4], afn[4], bfn[4];
    #pragma unroll
    for (int mf = 0; mf < 4; ++mf)
        af[mf] = *(const bf16x8*)(W + (size_t)(mf * 16 + ln) * KPAD + kbase + q * 8);
    #pragma unroll
    for (int nf = 0; nf < 4; ++nf)
        bfr[nf] = *(const bf16x8*)(Xt + (size_t)(l0 + nf * 16 + ln) * KPAD + kbase + q * 8);

    for (int ks = 0; ks < 6; ++ks) {
        if (ks + 1 < 6) {
            const int c = kbase + (ks + 1) * 32 + q * 8;
            #pragma unroll
            for (int mf = 0; mf < 4; ++mf)
                afn[mf] = *(const bf16x8*)(W + (size_t)(mf * 16 + ln) * KPAD + c);
            #pragma unroll
            for (int nf = 0; nf < 4; ++nf)
                bfn[nf] = *(const bf16x8*)(Xt + (size_t)(l0 + nf * 16 + ln) * KPAD + c);
        }
        #pragma unroll
        for (int mf = 0; mf < 4; ++mf)
            #pragma unroll
            for (int nf = 0; nf < 4; ++nf)
                acc[mf][nf] = __builtin_amdgcn_mfma_f32_16x16x32_bf16(
                    af[mf], bfr[nf], acc[mf][nf], 0, 0, 0);
        #pragma unroll
        for (int mf = 0; mf < 4; ++mf) af[mf] = afn[mf];
        #pragma unroll
        for (int nf = 0; nf < 4; ++nf) bfr[nf] = bfn[nf];
    }

    // cross-wave reduce: wave 1 -> LDS, wave 0 accumulates
    if (w == 1) {
        #pragma unroll
        for (int mf = 0; mf < 4; ++mf)
            #pragma unroll
            for (int nf = 0; nf < 4; ++nf)
                *(f32x4*)&red[lane][(mf * 4 + nf) * 4] = acc[mf][nf];
    }
    __syncthreads();
    if (w != 0) return;

    #pragma unroll
    for (int mf = 0; mf < 4; ++mf)
        #pragma unroll
        for (int nf = 0; nf < 4; ++nf) {
            const f32x4 p = *(const f32x4*)&red[lane][(mf * 4 + nf) * 4];
            acc[mf][nf] += p;
        }

    #pragma unroll
    for (int mf = 0; mf < 4; ++mf)
        #pragma unroll
        for (int r = 0; r < 4; ++r) {
            const float bb = bias[mf * 16 + q * 4 + r];
            #pragma unroll
            for (int nf = 0; nf < 4; ++nf) acc[mf][nf][r] += bb;
        }

    if (tensor < 2) {
        unsigned short* outp = (tensor ? kn : qn) + (size_t)b * L_DIM * 64;
        #pragma unroll
        for (int nf = 0; nf < 4; ++nf) {
            float s = 0.f;
            #pragma unroll
            for (int mf = 0; mf < 4; ++mf)
                #pragma unroll
                for (int r = 0; r < 4; ++r) s += acc[mf][nf][r] * acc[mf][nf][r];
            s += __shfl_xor(s, 16);
            s += __shfl_xor(s, 32);
            const float rn = 1.0f / fmaxf(sqrtf(s), 1e-6f);
            const size_t lrow = (size_t)(l0 + nf * 16 + ln) * 64;
            #pragma unroll
            for (int mf = 0; mf < 4; ++mf) {
                ushort4 o;
                o.x = f2bf(acc[mf][nf][0] * rn);
                o.y = f2bf(acc[mf][nf][1] * rn);
                o.z = f2bf(acc[mf][nf][2] * rn);
                o.w = f2bf(acc[mf][nf][3] * rn);
                *(ushort4*)(outp + lrow + mf * 16 + q * 4) = o;
            }
        }
    } else {
        unsigned short* outp = vbf + (size_t)b * 64 * L_DIM;
        #pragma unroll
        for (int mf = 0; mf < 4; ++mf)
            #pragma unroll
            for (int r = 0; r < 4; ++r) {
                const int v = mf * 16 + q * 4 + r;
                #pragma unroll
                for (int nf = 0; nf < 4; ++nf)
                    outp[(size_t)v * L_DIM + l0 + nf * 16 + ln] = f2bf(acc[mf][nf][r]);
            }
    }
}

// ---------------------------------------------------------------------------
// Kernel 3: attention, LDS-staged K/V, S^T/O^T formulation, bf16 partials.
// grid (32, NSPLIT, 2): x = 128-row i-tile, y = j-split, z = b. 4 waves;
// wave w owns i-strip [32w,32w+32) as two 16-row substrips (i = strip + ln).
//  S^T = mfma(A=K-frag, B=Q-frag): lane gets S[i=ln][j=jf*16+q*4+r]
//    -> P = exp(S) packed as ONE ds_write_b64 per (s,jf); rowsum per-lane.
//  O^T = mfma(A=V-frag, B=P-frag): lane gets O[i=ln][v=vf*16+q*4+r]
//    -> bf16 ushort4 epilogue stores.
// ---------------------------------------------------------------------------
__global__ __launch_bounds__(256) void attn_kernel(
    const unsigned short* __restrict__ qn, const unsigned short* __restrict__ kn,
    const unsigned short* __restrict__ vbf,
    unsigned short* __restrict__ opart, float* __restrict__ ssum)
{
    const int b = blockIdx.z, split = blockIdx.y;
    const int i0 = blockIdx.x * 128;
    const int tid = threadIdx.x;
    const int w = tid >> 6, lane = tid & 63, q = lane >> 4, ln = lane & 15;

    const unsigned short* Q = qn + (size_t)b * L_DIM * 64;   // [l][64]
    const unsigned short* K = kn + (size_t)b * L_DIM * 64;   // [l][64]
    const unsigned short* V = vbf + (size_t)b * 64 * L_DIM;  // [v][L]

    __shared__ unsigned short Kb[64][72];     // [j][d], +8 pad
    __shared__ unsigned short Vb[64][72];     // [v][j], +8 pad
    __shared__ unsigned short Pl[4][32][72];  // wave-private P strips [i][j]

    bf16x8 qa[2][2];
    #pragma unroll
    for (int s = 0; s < 2; ++s) {
        const unsigned short* qp = Q + (size_t)(i0 + w * 32 + s * 16 + ln) * 64 + q * 8;
        qa[s][0] = *(const bf16x8*)(qp);
        qa[s][1] = *(const bf16x8*)(qp + 32);
    }

    f32x4 acc[2][4];   // [s][vf]: O[i=ln][v=vf*16+q*4+r]
    #pragma unroll
    for (int s = 0; s < 2; ++s)
        #pragma unroll
        for (int vf = 0; vf < 4; ++vf) acc[s][vf] = (f32x4){0.f, 0.f, 0.f, 0.f};
    float rowsum[2] = {0.f, 0.f};
    const f32x4 zero = (f32x4){0.f, 0.f, 0.f, 0.f};

    const int jbase = split * (L_DIM / NSPLIT);
    const int JT = L_DIM / (NSPLIT * 64);   // 8 j-tiles per split

    bf16x8 kst[2], vst[2];
    #pragma unroll
    for (int p = 0; p < 2; ++p) {
        const int idx = p * 256 + tid;
        kst[p] = *(const bf16x8*)(K + (size_t)jbase * 64 + idx * 8);
        vst[p] = *(const bf16x8*)(V + (size_t)(idx >> 3) * L_DIM + jbase + (idx & 7) * 8);
    }
    #pragma unroll
    for (int p = 0; p < 2; ++p) {
        const int idx = p * 256 + tid;
        *(bf16x8*)&Kb[idx >> 3][(idx & 7) * 8] = kst[p];
        *(bf16x8*)&Vb[idx >> 3][(idx & 7) * 8] = vst[p];
    }
    __syncthreads();

    for (int jt = 0; jt < JT; ++jt) {
        if (jt + 1 < JT) {
            const int j0 = jbase + (jt + 1) * 64;
            #pragma unroll
            for (int p = 0; p < 2; ++p) {
                const int idx = p * 256 + tid;
                kst[p] = *(const bf16x8*)(K + (size_t)j0 * 64 + idx * 8);
                vst[p] = *(const bf16x8*)(V + (size_t)(idx >> 3) * L_DIM + j0 + (idx & 7) * 8);
            }
        }

        // K frags (A-operand): lane holds K[j=jf*16+ln][d=q*8..+7]
        bf16x8 kf[4][2];
        #pragma unroll
        for (int jf = 0; jf < 4; ++jf) {
            kf[jf][0] = *(const bf16x8*)&Kb[jf * 16 + ln][q * 8];
            kf[jf][1] = *(const bf16x8*)&Kb[jf * 16 + ln][q * 8 + 32];
        }

        // S^T = K.Q^T ; P = exp(S); b64 write j-contiguous into strip [i][j]
        #pragma unroll
        for (int s = 0; s < 2; ++s) {
            #pragma unroll
            for (int jf = 0; jf < 4; ++jf) {
                f32x4 st;
                st = __builtin_amdgcn_mfma_f32_16x16x32_bf16(kf[jf][0], qa[s][0], zero, 0, 0, 0);
                st = __builtin_amdgcn_mfma_f32_16x16x32_bf16(kf[jf][1], qa[s][1], st, 0, 0, 0);
                const float p0 = __expf(st[0]);
                const float p1 = __expf(st[1]);
                const float p2 = __expf(st[2]);
                const float p3 = __expf(st[3]);
                rowsum[s] += (p0 + p1) + (p2 + p3);
                ushort4 pk;
                pk.x = f2bf(p0); pk.y = f2bf(p1); pk.z = f2bf(p2); pk.w = f2bf(p3);
                *(ushort4*)&Pl[w][s * 16 + ln][jf * 16 + q * 4] = pk;
            }
        }

        // V frags (A-operand): lane holds V[v=vf*16+ln][j=q*8..+7]
        bf16x8 vfr[4][2];
        #pragma unroll
        for (int vf = 0; vf < 4; ++vf) {
            vfr[vf][0] = *(const bf16x8*)&Vb[vf * 16 + ln][q * 8];
            vfr[vf][1] = *(const bf16x8*)&Vb[vf * 16 + ln][q * 8 + 32];
        }

        // O^T += V.P^T  (P frag as B-operand: lane holds P[i=ln][j=q*8..+7])
        #pragma unroll
        for (int s = 0; s < 2; ++s) {
            const bf16x8 pb0 = *(const bf16x8*)&Pl[w][s * 16 + ln][q * 8];
            const bf16x8 pb1 = *(const bf16x8*)&Pl[w][s * 16 + ln][q * 8 + 32];
            #pragma unroll
            for (int vf = 0; vf < 4; ++vf) {
                acc[s][vf] = __builtin_amdgcn_mfma_f32_16x16x32_bf16(vfr[vf][0], pb0, acc[s][vf], 0, 0, 0);
                acc[s][vf] = __builtin_amdgcn_mfma_f32_16x16x32_bf16(vfr[vf][1], pb1, acc[s][vf], 0, 0, 0);
            }
        }

        __syncthreads();
        if (jt + 1 < JT) {
            #pragma unroll
            for (int p = 0; p < 2; ++p) {
                const int idx = p * 256 + tid;
                *(bf16x8*)&Kb[idx >> 3][(idx & 7) * 8] = kst[p];
                *(bf16x8*)&Vb[idx >> 3][(idx & 7) * 8] = vst[p];
            }
            __syncthreads();
        }
    }

    #pragma unroll
    for (int s = 0; s < 2; ++s) {
        rowsum[s] += __shfl_xor(rowsum[s], 16);
        rowsum[s] += __shfl_xor(rowsum[s], 32);
    }

    // O epilogue: bf16 ushort4 stores, i = strip + ln, v = vf*16+q*4..+3
    unsigned short* Op = opart + ((size_t)(b * NSPLIT + split) * L_DIM + i0 + w * 32) * 64;
    #pragma unroll
    for (int s = 0; s < 2; ++s)
        #pragma unroll
        for (int vf = 0; vf < 4; ++vf) {
            ushort4 o;
            o.x = f2bf(acc[s][vf][0]); o.y = f2bf(acc[s][vf][1]);
            o.z = f2bf(acc[s][vf][2]); o.w = f2bf(acc[s][vf][3]);
            *(ushort4*)&Op[(s * 16 + ln) * 64 + vf * 16 + q * 4] = o;
        }

    if (q == 0) {
        #pragma unroll
        for (int s = 0; s < 2; ++s)
            ssum[(size_t)(b * NSPLIT + split) * L_DIM + i0 + w * 32 + s * 16 + ln]
                = rowsum[s];
    }
}

// ---------------------------------------------------------------------------
// Kernel 4: sum the NSPLIT bf16 partials, divide by rowsum, transpose to
// out [b][v][l] fp32.
// ---------------------------------------------------------------------------
__global__ __launch_bounds__(256) void combine_kernel(
    const unsigned short* __restrict__ opart, const float* __restrict__ ssum,
    float* __restrict__ out)
{
    const int b = blockIdx.y;
    const int i0 = blockIdx.x * 64;
    const int tid = threadIdx.x;
    __shared__ float t[64][65];
    __shared__ float sinv[64];

    if (tid < 64) {
        float s = 0.f;
        for (int sp = 0; sp < NSPLIT; ++sp)
            s += ssum[(size_t)(b * NSPLIT + sp) * L_DIM + i0 + tid];
        sinv[tid] = 1.0f / s;
    }
    __syncthreads();
    for (int it = 0; it < 4; ++it) {
        const int idx = tid + it * 256;          // 1024: (i, vq)
        const int i = idx >> 4, vq = idx & 15;
        float a0 = 0.f, a1 = 0.f, a2 = 0.f, a3 = 0.f;
        for (int sp = 0; sp < NSPLIT; ++sp) {
            const ushort4 p = *(const ushort4*)&opart[
                (((size_t)(b * NSPLIT + sp) * L_DIM + i0 + i)) * 64 + vq * 4];
            a0 += bf2f(p.x); a1 += bf2f(p.y); a2 += bf2f(p.z); a3 += bf2f(p.w);
        }
        t[i][vq * 4 + 0] = a0;
        t[i][vq * 4 + 1] = a1;
        t[i][vq * 4 + 2] = a2;
        t[i][vq * 4 + 3] = a3;
    }
    __syncthreads();
    for (int idx = tid; idx < 4096; idx += 256) {
        const int v = idx >> 6, i = idx & 63;
        out[((size_t)(b * 64 + v)) * L_DIM + i0 + i] = t[i][v] * sinv[i];
    }
}

// ---------------------------------------------------------------------------
extern "C" void kernel_launch(void* const* d_in, const int* in_sizes, int n_in,
                              void* d_out, int out_size, void* d_ws, size_t ws_size,
                              hipStream_t stream)
{
    const float* x  = (const float*)d_in[0];
    const float* xe = (const float*)d_in[1];
    const float* Wq = (const float*)d_in[2];
    const float* bq = (const float*)d_in[3];
    const float* Wk = (const float*)d_in[4];
    const float* bk = (const float*)d_in[5];
    const float* Wv = (const float*)d_in[6];
    const float* bv = (const float*)d_in[7];
    float* out = (float*)d_out;

    // ws layout (24 MB used, no overlays): op is bf16 now (8 MB).
    char* ws = (char*)d_ws;
    unsigned short* qn   = (unsigned short*)(ws);                    // 0..1 MB
    unsigned short* kn   = (unsigned short*)(ws + (1u << 20));       // 1..2 MB
    unsigned short* vbf  = (unsigned short*)(ws + (2u << 20));       // 2..3 MB
    float*          ss   = (float*)(ws + (3u << 20));                // 3..3.25 MB
    unsigned short* wb   = (unsigned short*)(ws + (3u << 20) + (512u << 10));
    unsigned short* xtxe = (unsigned short*)(ws + (4u << 20));       // 4..10 MB
    unsigned short* xtx  = (unsigned short*)(ws + (10u << 20));      // 10..16 MB
    unsigned short* op   = (unsigned short*)(ws + (16u << 20));      // 16..24 MB

    prep_kernel<<<dim3(64, 6, 5), 256, 0, stream>>>(x, xe, Wq, Wk, Wv, xtx, xtxe, wb);
    proj_kernel<<<dim3(64, 6), 128, 0, stream>>>(xtxe, xtx, wb, bq, bk, bv, qn, kn, vbf);
    attn_kernel<<<dim3(32, NSPLIT, 2), 256, 0, stream>>>(qn, kn, vbf, op, ss);
    combine_kernel<<<dim3(64, 2), 256, 0, stream>>>(op, ss, out);
}